// Round 8
// baseline (111.654 us; speedup 1.0000x reference)
//
#include <hip/hip_runtime.h>

// SubTokenEmbedding: fused embedding gather + sorted-segment sum pooling.
//
// *** DIAGNOSTIC ROUND: main kernel runs its entire body REPS=2 times
// *** (identical outputs, idempotent). This pushes its single dispatch above
// *** the harness fillBuffer dispatches so rocprof's top-5 finally shows its
// *** FETCH/WRITE/VALUBusy/Occupancy. rep 2 executes with warm caches ->
// *** counters disambiguate steady-state-churn vs cold-miss-only gather.
//
// Structure = R5 best (66.0 us): prep (bf16 ctab + starts), then one full
// wave (64 lanes) per SPG consecutive segments, uint/lane row loads,
// readlane->SGPR scalar flush branches, nt streams.

#define H_EMB   128
#define SPG     8       // segments per wave
#define UNROLL  16      // table-row loads kept in flight per wave
#define ROW_U1  64      // uint per bf16 row (64 x 4 B = 256 B)
#define REPS    2       // DIAGNOSTIC: recompute factor

__device__ __forceinline__ unsigned f2bf_rne(float f) {
    unsigned u = __float_as_uint(f);
    return (u + 0x7FFFu + ((u >> 16) & 1u)) >> 16;   // round-to-nearest-even
}

__device__ __forceinline__ void nt_store2(float* p, float x, float y) {
    unsigned long long v = (unsigned long long)__float_as_uint(x)
                         | ((unsigned long long)__float_as_uint(y) << 32);
    __builtin_nontemporal_store(v, (unsigned long long*)p);
}

__global__ __launch_bounds__(256)
void prep_kernel(const float* __restrict__ t, unsigned* __restrict__ ct, int n_pairs,
                 const int* __restrict__ segs, int* __restrict__ starts,
                 int n, int n_nodes)
{
    const int i = blockIdx.x * blockDim.x + threadIdx.x;
    if (i < n_pairs) {
        unsigned long long w =
            __builtin_nontemporal_load((const unsigned long long*)t + i);
        const float fx = __uint_as_float((unsigned)w);
        const float fy = __uint_as_float((unsigned)(w >> 32));
        ct[i] = f2bf_rne(fx) | (f2bf_rne(fy) << 16);
    }
    if (i < n) {
        const int s  = __builtin_nontemporal_load(segs + i);
        const int sp = (i == 0) ? -1 : __builtin_nontemporal_load(segs + i - 1);
        for (int seg = sp + 1; seg <= s; ++seg) starts[seg] = i;   // run-starts + gaps
        if (i == n - 1)
            for (int seg = s + 1; seg <= n_nodes; ++seg) starts[seg] = n;
    }
}

// -------- bf16-table main kernel: one wave per SPG segments --------
__global__ __launch_bounds__(256)
void SubTokenEmbedding_6734508720780_kernel(
    const unsigned* __restrict__ ctab,   // bf16-packed table, ROW_U1 uint/row
    const int*      __restrict__ ids,
    const int*      __restrict__ segs,
    const int*      __restrict__ starts, // [n_nodes+1]
    float*          __restrict__ out,
    int n_nodes)
{
    const int wave = (int)((blockIdx.x * blockDim.x + threadIdx.x) >> 6);
    const int lane = (int)(threadIdx.x & 63);
    const int s0   = wave * SPG;
    if (s0 >= n_nodes) return;
    const int s_end = min(s0 + SPG, n_nodes);

    const int beg = starts[s0];
    const int end = starts[s_end];

    const unsigned* trow = ctab + lane;          // lane l reads uint #l of each row
    float*          orow = out  + lane * 2;      // lane l owns floats 2l, 2l+1

    for (int rep = 0; rep < REPS; ++rep) {       // DIAGNOSTIC loop: identical work
        float accx = 0.f, accy = 0.f;
        int cur = s0;

        int sv = 0, iv = 0;
        if (beg + lane < end) {
            sv = __builtin_nontemporal_load(segs + beg + lane);
            iv = __builtin_nontemporal_load(ids  + beg + lane);
        }

        for (int base = beg; base < end; base += 64) {
            const int cnt = min(64, end - base);
            const int nb  = base + 64;
            int sv2 = 0, iv2 = 0;
            if (nb + lane < end) {
                sv2 = __builtin_nontemporal_load(segs + nb + lane);
                iv2 = __builtin_nontemporal_load(ids  + nb + lane);
            }

            for (int k = 0; k < cnt; k += UNROLL) {
                int s_a[UNROLL], id_a[UNROLL];
                #pragma unroll
                for (int u = 0; u < UNROLL; ++u) {
                    s_a[u]  = __builtin_amdgcn_readlane(sv, k + u);   // -> SGPR
                    id_a[u] = __builtin_amdgcn_readlane(iv, k + u);   // -> SGPR
                }
                unsigned tv[UNROLL];
                #pragma unroll
                for (int u = 0; u < UNROLL; ++u)
                    tv[u] = trow[(size_t)id_a[u] * ROW_U1];

                #pragma unroll
                for (int u = 0; u < UNROLL; ++u) {
                    if (k + u < cnt) {                       // scalar branch
                        const int s = s_a[u];
                        if (s != cur) {                      // scalar branch
                            nt_store2(orow + (size_t)cur * H_EMB, accx, accy);
                            accx = 0.f; accy = 0.f;
                            for (int z = cur + 1; z < s; ++z)
                                nt_store2(orow + (size_t)z * H_EMB, 0.f, 0.f);
                            cur = s;
                        }
                        accx += __uint_as_float(tv[u] << 16);
                        accy += __uint_as_float(tv[u] & 0xFFFF0000u);
                    }
                }
            }
            sv = sv2; iv = iv2;
        }

        nt_store2(orow + (size_t)cur * H_EMB, accx, accy);
        for (int z = cur + 1; z < s_end; ++z)
            nt_store2(orow + (size_t)z * H_EMB, 0.f, 0.f);
    }
}

// -------- f32 fallback (ws too small for bf16 table / starts) --------
__global__ __launch_bounds__(256)
void subtok_f32_kernel(
    const float* __restrict__ table,
    const int*   __restrict__ ids,
    const int*   __restrict__ segs,
    float*       __restrict__ out,
    int total_subtokens, int n_nodes)
{
    const int group = (int)((blockIdx.x * blockDim.x + threadIdx.x) / 32);
    const int lane  = (int)(threadIdx.x & 31);
    const int s0    = group * SPG;
    if (s0 >= n_nodes) return;
    const int s_end = min(s0 + SPG, n_nodes);

    auto lower_bound = [&](int v) -> int {
        int lo = 0, hi = total_subtokens;
        while (lo < hi) { int m = (lo + hi) >> 1; if (segs[m] < v) lo = m + 1; else hi = m; }
        return lo;
    };
    const int beg = lower_bound(s0);
    const int end = lower_bound(s_end);

    const float* trow = table + (size_t)lane * 4;
    float*       orow = out   + (size_t)lane * 4;
    float4 acc = make_float4(0.f, 0.f, 0.f, 0.f);
    int cur = s0;

    for (int j = beg; j < end; ++j) {
        const int s  = segs[j];
        const int id = ids[j];
        if (s != cur) {
            *reinterpret_cast<float4*>(orow + (size_t)cur * H_EMB) = acc;
            const float4 zero = make_float4(0.f, 0.f, 0.f, 0.f);
            for (int z = cur + 1; z < s; ++z)
                *reinterpret_cast<float4*>(orow + (size_t)z * H_EMB) = zero;
            acc = zero; cur = s;
        }
        const float4 t = *reinterpret_cast<const float4*>(trow + (size_t)id * H_EMB);
        acc.x += t.x; acc.y += t.y; acc.z += t.z; acc.w += t.w;
    }
    *reinterpret_cast<float4*>(orow + (size_t)cur * H_EMB) = acc;
    const float4 zero = make_float4(0.f, 0.f, 0.f, 0.f);
    for (int z = cur + 1; z < s_end; ++z)
        *reinterpret_cast<float4*>(orow + (size_t)z * H_EMB) = zero;
}

extern "C" void kernel_launch(void* const* d_in, const int* in_sizes, int n_in,
                              void* d_out, int out_size, void* d_ws, size_t ws_size,
                              hipStream_t stream) {
    const float* table = (const float*)d_in[0];
    const int*   ids   = (const int*)d_in[1];
    const int*   segs  = (const int*)d_in[2];
    float*       out   = (float*)d_out;

    const int total_subtokens = in_sizes[1];
    const int vocab           = in_sizes[0] / H_EMB;
    const int n_nodes         = out_size / H_EMB;    // out is [n_nodes, 128]

    const size_t starts_bytes = ((size_t)(n_nodes + 1) * sizeof(int) + 15) & ~(size_t)15;
    const size_t ctab_bytes   = (size_t)vocab * (H_EMB / 2) * sizeof(unsigned); // 256 B/row
    const int    n_pairs      = vocab * (H_EMB / 2);

    if (ws_size >= starts_bytes + ctab_bytes) {
        int*      starts = (int*)d_ws;
        unsigned* ctab   = (unsigned*)((char*)d_ws + starts_bytes);

        const int prep_n = max(n_pairs, total_subtokens);
        prep_kernel<<<(prep_n + 255) / 256, 256, 0, stream>>>(
            table, ctab, n_pairs, segs, starts, total_subtokens, n_nodes);

        const int n_waves  = (n_nodes + SPG - 1) / SPG;
        const int n_blocks = (n_waves + 3) / 4;          // 4 waves per 256-thread block
        SubTokenEmbedding_6734508720780_kernel<<<n_blocks, 256, 0, stream>>>(
            ctab, ids, segs, starts, out, n_nodes);
    } else {
        const int n_groups = (n_nodes + SPG - 1) / SPG;
        const int n_blocks = (n_groups + 7) / 8;
        subtok_f32_kernel<<<n_blocks, 256, 0, stream>>>(
            table, ids, segs, out, total_subtokens, n_nodes);
    }
}

// Round 9
// 88.404 us; speedup vs baseline: 1.2630x; 1.2630x over previous
//
#include <hip/hip_runtime.h>

// SubTokenEmbedding: fused embedding gather + sorted-segment sum pooling.
//
// *** DIAGNOSTIC ROUND 2: pass 1 = full correct kernel (R5 structure).
// *** pass 2 (same dispatch) = PURE GATHER over the same id stream: no seg
// *** logic, no guards, no stores; dummy acc kept live via empty asm so it
// *** can't be DCE'd. dur_us - 66 reads out the pure gather cost directly:
// ***   ~45 us -> gather-service-bound (declare roofline)
// ***   ~10-20 us -> VALU/bookkeeping/MLP-bound (restructure next round)

#define H_EMB   128
#define SPG     8       // segments per wave
#define UNROLL  16      // table-row loads kept in flight per wave
#define ROW_U1  64      // uint per bf16 row (64 x 4 B = 256 B)

__device__ __forceinline__ unsigned f2bf_rne(float f) {
    unsigned u = __float_as_uint(f);
    return (u + 0x7FFFu + ((u >> 16) & 1u)) >> 16;   // round-to-nearest-even
}

__device__ __forceinline__ void nt_store2(float* p, float x, float y) {
    unsigned long long v = (unsigned long long)__float_as_uint(x)
                         | ((unsigned long long)__float_as_uint(y) << 32);
    __builtin_nontemporal_store(v, (unsigned long long*)p);
}

__global__ __launch_bounds__(256)
void prep_kernel(const float* __restrict__ t, unsigned* __restrict__ ct, int n_pairs,
                 const int* __restrict__ segs, int* __restrict__ starts,
                 int n, int n_nodes)
{
    const int i = blockIdx.x * blockDim.x + threadIdx.x;
    if (i < n_pairs) {
        unsigned long long w =
            __builtin_nontemporal_load((const unsigned long long*)t + i);
        const float fx = __uint_as_float((unsigned)w);
        const float fy = __uint_as_float((unsigned)(w >> 32));
        ct[i] = f2bf_rne(fx) | (f2bf_rne(fy) << 16);
    }
    if (i < n) {
        const int s  = __builtin_nontemporal_load(segs + i);
        const int sp = (i == 0) ? -1 : __builtin_nontemporal_load(segs + i - 1);
        for (int seg = sp + 1; seg <= s; ++seg) starts[seg] = i;   // run-starts + gaps
        if (i == n - 1)
            for (int seg = s + 1; seg <= n_nodes; ++seg) starts[seg] = n;
    }
}

// -------- bf16-table main kernel: one wave per SPG segments --------
__global__ __launch_bounds__(256)
void SubTokenEmbedding_6734508720780_kernel(
    const unsigned* __restrict__ ctab,   // bf16-packed table, ROW_U1 uint/row
    const int*      __restrict__ ids,
    const int*      __restrict__ segs,
    const int*      __restrict__ starts, // [n_nodes+1]
    float*          __restrict__ out,
    int n_nodes)
{
    const int wave = (int)((blockIdx.x * blockDim.x + threadIdx.x) >> 6);
    const int lane = (int)(threadIdx.x & 63);
    const int s0   = wave * SPG;
    if (s0 >= n_nodes) return;
    const int s_end = min(s0 + SPG, n_nodes);

    const int beg = starts[s0];
    const int end = starts[s_end];

    const unsigned* trow = ctab + lane;          // lane l reads uint #l of each row
    float*          orow = out  + lane * 2;      // lane l owns floats 2l, 2l+1

    // ---------------- pass 1: full, correct ----------------
    {
        float accx = 0.f, accy = 0.f;
        int cur = s0;

        int sv = 0, iv = 0;
        if (beg + lane < end) {
            sv = __builtin_nontemporal_load(segs + beg + lane);
            iv = __builtin_nontemporal_load(ids  + beg + lane);
        }

        for (int base = beg; base < end; base += 64) {
            const int cnt = min(64, end - base);
            const int nb  = base + 64;
            int sv2 = 0, iv2 = 0;
            if (nb + lane < end) {
                sv2 = __builtin_nontemporal_load(segs + nb + lane);
                iv2 = __builtin_nontemporal_load(ids  + nb + lane);
            }

            for (int k = 0; k < cnt; k += UNROLL) {
                int s_a[UNROLL], id_a[UNROLL];
                #pragma unroll
                for (int u = 0; u < UNROLL; ++u) {
                    s_a[u]  = __builtin_amdgcn_readlane(sv, k + u);   // -> SGPR
                    id_a[u] = __builtin_amdgcn_readlane(iv, k + u);   // -> SGPR
                }
                unsigned tv[UNROLL];
                #pragma unroll
                for (int u = 0; u < UNROLL; ++u)
                    tv[u] = trow[(size_t)id_a[u] * ROW_U1];

                #pragma unroll
                for (int u = 0; u < UNROLL; ++u) {
                    if (k + u < cnt) {                       // scalar branch
                        const int s = s_a[u];
                        if (s != cur) {                      // scalar branch
                            nt_store2(orow + (size_t)cur * H_EMB, accx, accy);
                            accx = 0.f; accy = 0.f;
                            for (int z = cur + 1; z < s; ++z)
                                nt_store2(orow + (size_t)z * H_EMB, 0.f, 0.f);
                            cur = s;
                        }
                        accx += __uint_as_float(tv[u] << 16);
                        accy += __uint_as_float(tv[u] & 0xFFFF0000u);
                    }
                }
            }
            sv = sv2; iv = iv2;
        }

        nt_store2(orow + (size_t)cur * H_EMB, accx, accy);
        for (int z = cur + 1; z < s_end; ++z)
            nt_store2(orow + (size_t)z * H_EMB, 0.f, 0.f);
    }

    // ---------------- pass 2: PURE GATHER diagnostic ----------------
    // Same id stream, same gather pattern; no seg logic, no guards inside the
    // UNROLL body (tail over-gathers row 0 into the dummy acc: harmless),
    // no stores. Result kept live via empty inline asm (anti-DCE).
    {
        float dx = 0.f, dy = 0.f;
        int iv = 0;
        if (beg + lane < end)
            iv = __builtin_nontemporal_load(ids + beg + lane);

        for (int base = beg; base < end; base += 64) {
            const int cnt = min(64, end - base);
            const int nb  = base + 64;
            int iv2 = 0;
            if (nb + lane < end)
                iv2 = __builtin_nontemporal_load(ids + nb + lane);

            for (int k = 0; k < cnt; k += UNROLL) {
                int id_a[UNROLL];
                #pragma unroll
                for (int u = 0; u < UNROLL; ++u)
                    id_a[u] = __builtin_amdgcn_readlane(iv, k + u);
                unsigned tv[UNROLL];
                #pragma unroll
                for (int u = 0; u < UNROLL; ++u)
                    tv[u] = trow[(size_t)id_a[u] * ROW_U1];
                #pragma unroll
                for (int u = 0; u < UNROLL; ++u) {
                    dx += __uint_as_float(tv[u] << 16);
                    dy += __uint_as_float(tv[u] & 0xFFFF0000u);
                }
            }
            iv = iv2;
        }
        asm volatile("" :: "v"(dx), "v"(dy));   // keep pass-2 work alive, no store
    }
}

// -------- f32 fallback (ws too small for bf16 table / starts) --------
__global__ __launch_bounds__(256)
void subtok_f32_kernel(
    const float* __restrict__ table,
    const int*   __restrict__ ids,
    const int*   __restrict__ segs,
    float*       __restrict__ out,
    int total_subtokens, int n_nodes)
{
    const int group = (int)((blockIdx.x * blockDim.x + threadIdx.x) / 32);
    const int lane  = (int)(threadIdx.x & 31);
    const int s0    = group * SPG;
    if (s0 >= n_nodes) return;
    const int s_end = min(s0 + SPG, n_nodes);

    auto lower_bound = [&](int v) -> int {
        int lo = 0, hi = total_subtokens;
        while (lo < hi) { int m = (lo + hi) >> 1; if (segs[m] < v) lo = m + 1; else hi = m; }
        return lo;
    };
    const int beg = lower_bound(s0);
    const int end = lower_bound(s_end);

    const float* trow = table + (size_t)lane * 4;
    float*       orow = out   + (size_t)lane * 4;
    float4 acc = make_float4(0.f, 0.f, 0.f, 0.f);
    int cur = s0;

    for (int j = beg; j < end; ++j) {
        const int s  = segs[j];
        const int id = ids[j];
        if (s != cur) {
            *reinterpret_cast<float4*>(orow + (size_t)cur * H_EMB) = acc;
            const float4 zero = make_float4(0.f, 0.f, 0.f, 0.f);
            for (int z = cur + 1; z < s; ++z)
                *reinterpret_cast<float4*>(orow + (size_t)z * H_EMB) = zero;
            acc = zero; cur = s;
        }
        const float4 t = *reinterpret_cast<const float4*>(trow + (size_t)id * H_EMB);
        acc.x += t.x; acc.y += t.y; acc.z += t.z; acc.w += t.w;
    }
    *reinterpret_cast<float4*>(orow + (size_t)cur * H_EMB) = acc;
    const float4 zero = make_float4(0.f, 0.f, 0.f, 0.f);
    for (int z = cur + 1; z < s_end; ++z)
        *reinterpret_cast<float4*>(orow + (size_t)z * H_EMB) = zero;
}

extern "C" void kernel_launch(void* const* d_in, const int* in_sizes, int n_in,
                              void* d_out, int out_size, void* d_ws, size_t ws_size,
                              hipStream_t stream) {
    const float* table = (const float*)d_in[0];
    const int*   ids   = (const int*)d_in[1];
    const int*   segs  = (const int*)d_in[2];
    float*       out   = (float*)d_out;

    const int total_subtokens = in_sizes[1];
    const int vocab           = in_sizes[0] / H_EMB;
    const int n_nodes         = out_size / H_EMB;    // out is [n_nodes, 128]

    const size_t starts_bytes = ((size_t)(n_nodes + 1) * sizeof(int) + 15) & ~(size_t)15;
    const size_t ctab_bytes   = (size_t)vocab * (H_EMB / 2) * sizeof(unsigned); // 256 B/row
    const int    n_pairs      = vocab * (H_EMB / 2);

    if (ws_size >= starts_bytes + ctab_bytes) {
        int*      starts = (int*)d_ws;
        unsigned* ctab   = (unsigned*)((char*)d_ws + starts_bytes);

        const int prep_n = max(n_pairs, total_subtokens);
        prep_kernel<<<(prep_n + 255) / 256, 256, 0, stream>>>(
            table, ctab, n_pairs, segs, starts, total_subtokens, n_nodes);

        const int n_waves  = (n_nodes + SPG - 1) / SPG;
        const int n_blocks = (n_waves + 3) / 4;          // 4 waves per 256-thread block
        SubTokenEmbedding_6734508720780_kernel<<<n_blocks, 256, 0, stream>>>(
            ctab, ids, segs, starts, out, n_nodes);
    } else {
        const int n_groups = (n_nodes + SPG - 1) / SPG;
        const int n_blocks = (n_groups + 7) / 8;
        subtok_f32_kernel<<<n_blocks, 256, 0, stream>>>(
            table, ids, segs, out, total_subtokens, n_nodes);
    }
}

// Round 11
// 64.527 us; speedup vs baseline: 1.7303x; 1.3700x over previous
//
#include <hip/hip_runtime.h>

// SubTokenEmbedding: fused embedding gather + sorted-segment sum pooling.
//
// out[s, :] = sum_{i : segs[i]==s} table[ids[i], :]     (segs sorted ascending)
//
// Measured structure of the problem (R7/R9 diagnostics):
//   - random 256 B table-gather misses are served at ~3.0-3.2 TB/s (invariant
//     under warm caches, L2-sized working sets, and non-temporal streams)
//   - the main kernel runs at ~95% of the resulting mixed-service roofline
// So the main kernel keeps the R5 wave-per-SPG-segments structure; this round
// only removes residual overhead: SPG=16 (half the waves), a guard-free
// always-64 inner batch (OOR lanes read id=0 -> the all-zero PAD row, and
// seg=segs[end-1] -> flush-neutral sentinel), and a vectorized prep.
//
// No atomics; every output element written exactly once per launch, so the
// poisoned d_out needs no pre-zeroing.

#define H_EMB   128
#define SPG     16      // segments per wave
#define UNROLL  16      // table-row loads kept in flight per wave
#define ROW_U1  64      // uint per bf16 row (64 x 4 B = 256 B)

__device__ __forceinline__ unsigned f2bf_rne(float f) {
    unsigned u = __float_as_uint(f);
    return (u + 0x7FFFu + ((u >> 16) & 1u)) >> 16;   // round-to-nearest-even
}

__device__ __forceinline__ void nt_store2(float* p, float x, float y) {
    unsigned long long v = (unsigned long long)__float_as_uint(x)
                         | ((unsigned long long)__float_as_uint(y) << 32);
    __builtin_nontemporal_store(v, (unsigned long long*)p);
}

__global__ __launch_bounds__(256)
void prep_kernel(const float* __restrict__ t, uint2* __restrict__ ct, int n_quads,
                 const int* __restrict__ segs, int* __restrict__ starts,
                 int n, int n_nodes)
{
    const int i = blockIdx.x * blockDim.x + threadIdx.x;
    if (i < n_quads) {           // 4 f32 -> 2 packed bf16x2 per thread
        // nontemporal builtin needs scalar pointer types: two ull loads = 16 B
        const unsigned long long w0 = __builtin_nontemporal_load(
            reinterpret_cast<const unsigned long long*>(t) + 2 * (size_t)i);
        const unsigned long long w1 = __builtin_nontemporal_load(
            reinterpret_cast<const unsigned long long*>(t) + 2 * (size_t)i + 1);
        const float fx = __uint_as_float((unsigned)w0);
        const float fy = __uint_as_float((unsigned)(w0 >> 32));
        const float fz = __uint_as_float((unsigned)w1);
        const float fw = __uint_as_float((unsigned)(w1 >> 32));
        uint2 p;
        p.x = f2bf_rne(fx) | (f2bf_rne(fy) << 16);
        p.y = f2bf_rne(fz) | (f2bf_rne(fw) << 16);
        ct[i] = p;               // normal store: gathered next, want it cached
    }
    if (i < n) {
        const int s  = segs[i];
        const int sp = (i == 0) ? -1 : segs[i - 1];
        for (int seg = sp + 1; seg <= s; ++seg) starts[seg] = i;   // run-starts + gaps
        if (i == n - 1)
            for (int seg = s + 1; seg <= n_nodes; ++seg) starts[seg] = n;
    }
}

// -------- bf16-table main kernel: one wave per SPG segments --------
__global__ __launch_bounds__(256)
void SubTokenEmbedding_6734508720780_kernel(
    const unsigned* __restrict__ ctab,   // bf16-packed table, ROW_U1 uint/row
    const int*      __restrict__ ids,
    const int*      __restrict__ segs,
    const int*      __restrict__ starts, // [n_nodes+1]
    float*          __restrict__ out,
    int n_nodes)
{
    const int wave = (int)((blockIdx.x * blockDim.x + threadIdx.x) >> 6);
    const int lane = (int)(threadIdx.x & 63);
    const int s0   = wave * SPG;
    if (s0 >= n_nodes) return;
    const int s_end = min(s0 + SPG, n_nodes);

    const int beg = starts[s0];
    const int end = starts[s_end];

    const unsigned* trow = ctab + lane;          // lane l reads uint #l of each row
    float*          orow = out  + lane * 2;      // lane l owns floats 2l, 2l+1

    float accx = 0.f, accy = 0.f;
    int cur = s0;

    if (beg < end) {
        // Batch loads are CLAMPED to end-1 so every batch is a full 64 rows:
        //   OOR lane: seg = segs[end-1] (== cur by then -> never flushes),
        //             id  = 0          (PAD row, all zeros -> acc += 0).
        // This removes the cnt computation and the per-row guard branch.
        const int last = end - 1;
        int idx0 = beg + lane;
        int c0   = min(idx0, last);
        int sv   = __builtin_nontemporal_load(segs + c0);
        int iv   = (idx0 < end) ? __builtin_nontemporal_load(ids + c0) : 0;

        for (int base = beg; base < end; base += 64) {
            const int nb = base + 64;
            int sv2 = 0, iv2 = 0;
            if (nb < end) {
                const int idx = nb + lane;
                const int c   = min(idx, last);
                sv2 = __builtin_nontemporal_load(segs + c);
                iv2 = (idx < end) ? __builtin_nontemporal_load(ids + c) : 0;
            }

            #pragma unroll
            for (int k = 0; k < 64; k += UNROLL) {
                int s_a[UNROLL], id_a[UNROLL];
                #pragma unroll
                for (int u = 0; u < UNROLL; ++u) {
                    s_a[u]  = __builtin_amdgcn_readlane(sv, k + u);   // -> SGPR
                    id_a[u] = __builtin_amdgcn_readlane(iv, k + u);   // -> SGPR
                }
                unsigned tv[UNROLL];
                #pragma unroll
                for (int u = 0; u < UNROLL; ++u)
                    tv[u] = trow[(size_t)id_a[u] * ROW_U1];

                #pragma unroll
                for (int u = 0; u < UNROLL; ++u) {
                    const int s = s_a[u];
                    if (s != cur) {                      // scalar branch (rare)
                        nt_store2(orow + (size_t)cur * H_EMB, accx, accy);
                        accx = 0.f; accy = 0.f;
                        for (int z = cur + 1; z < s; ++z)
                            nt_store2(orow + (size_t)z * H_EMB, 0.f, 0.f);
                        cur = s;
                    }
                    accx += __uint_as_float(tv[u] << 16);
                    accy += __uint_as_float(tv[u] & 0xFFFF0000u);
                }
            }
            sv = sv2; iv = iv2;
        }
    }

    // final flush: cur, then zeros through s_end-1
    nt_store2(orow + (size_t)cur * H_EMB, accx, accy);
    for (int z = cur + 1; z < s_end; ++z)
        nt_store2(orow + (size_t)z * H_EMB, 0.f, 0.f);
}

// -------- f32 fallback (ws too small for bf16 table / starts) --------
__global__ __launch_bounds__(256)
void subtok_f32_kernel(
    const float* __restrict__ table,
    const int*   __restrict__ ids,
    const int*   __restrict__ segs,
    float*       __restrict__ out,
    int total_subtokens, int n_nodes)
{
    const int group = (int)((blockIdx.x * blockDim.x + threadIdx.x) / 32);
    const int lane  = (int)(threadIdx.x & 31);
    const int s0    = group * SPG;
    if (s0 >= n_nodes) return;
    const int s_end = min(s0 + SPG, n_nodes);

    auto lower_bound = [&](int v) -> int {
        int lo = 0, hi = total_subtokens;
        while (lo < hi) { int m = (lo + hi) >> 1; if (segs[m] < v) lo = m + 1; else hi = m; }
        return lo;
    };
    const int beg = lower_bound(s0);
    const int end = lower_bound(s_end);

    const float* trow = table + (size_t)lane * 4;
    float*       orow = out   + (size_t)lane * 4;
    float4 acc = make_float4(0.f, 0.f, 0.f, 0.f);
    int cur = s0;

    for (int j = beg; j < end; ++j) {
        const int s  = segs[j];
        const int id = ids[j];
        if (s != cur) {
            *reinterpret_cast<float4*>(orow + (size_t)cur * H_EMB) = acc;
            const float4 zero = make_float4(0.f, 0.f, 0.f, 0.f);
            for (int z = cur + 1; z < s; ++z)
                *reinterpret_cast<float4*>(orow + (size_t)z * H_EMB) = zero;
            acc = zero; cur = s;
        }
        const float4 t = *reinterpret_cast<const float4*>(trow + (size_t)id * H_EMB);
        acc.x += t.x; acc.y += t.y; acc.z += t.z; acc.w += t.w;
    }
    *reinterpret_cast<float4*>(orow + (size_t)cur * H_EMB) = acc;
    const float4 zero = make_float4(0.f, 0.f, 0.f, 0.f);
    for (int z = cur + 1; z < s_end; ++z)
        *reinterpret_cast<float4*>(orow + (size_t)z * H_EMB) = zero;
}

extern "C" void kernel_launch(void* const* d_in, const int* in_sizes, int n_in,
                              void* d_out, int out_size, void* d_ws, size_t ws_size,
                              hipStream_t stream) {
    const float* table = (const float*)d_in[0];
    const int*   ids   = (const int*)d_in[1];
    const int*   segs  = (const int*)d_in[2];
    float*       out   = (float*)d_out;

    const int total_subtokens = in_sizes[1];
    const int vocab           = in_sizes[0] / H_EMB;
    const int n_nodes         = out_size / H_EMB;    // out is [n_nodes, 128]

    const size_t starts_bytes = ((size_t)(n_nodes + 1) * sizeof(int) + 15) & ~(size_t)15;
    const size_t ctab_bytes   = (size_t)vocab * (H_EMB / 2) * sizeof(unsigned); // 256 B/row
    const int    n_quads      = vocab * (H_EMB / 4);   // 4 f32 per prep thread

    if (ws_size >= starts_bytes + ctab_bytes) {
        int*   starts = (int*)d_ws;
        uint2* ctab   = (uint2*)((char*)d_ws + starts_bytes);

        const int prep_n = max(n_quads, total_subtokens);
        prep_kernel<<<(prep_n + 255) / 256, 256, 0, stream>>>(
            table, ctab, n_quads, segs, starts, total_subtokens, n_nodes);

        const int n_waves  = (n_nodes + SPG - 1) / SPG;
        const int n_blocks = (n_waves + 3) / 4;          // 4 waves per 256-thread block
        SubTokenEmbedding_6734508720780_kernel<<<n_blocks, 256, 0, stream>>>(
            (const unsigned*)ctab, ids, segs, starts, out, n_nodes);
    } else {
        const int n_groups = (n_nodes + SPG - 1) / SPG;
        const int n_blocks = (n_groups + 7) / 8;
        subtok_f32_kernel<<<n_blocks, 256, 0, stream>>>(
            table, ids, segs, out, total_subtokens, n_nodes);
    }
}